// Round 1
// baseline (328.574 us; speedup 1.0000x reference)
//
#include <hip/hip_runtime.h>
#include <cmath>

#define NB 128
static constexpr float CUT  = 6.0f;
static constexpr float STEP = CUT / (NB - 1);
static constexpr float GAM  = (NB - 1) / CUT;          // 1 / mean spacing
static constexpr float PIF  = 3.14159265358979f;

// Evaluate density/pair splines and their radial derivatives at bond length u.
// spd = softplus(phi_density), pp = phi_pair (both staged in LDS).
// Returns {dens, ddens, pair, dpair}.
__device__ __forceinline__ float4 spline_eval(float u,
                                              const float* __restrict__ spd,
                                              const float* __restrict__ pp) {
    float ang  = u * (PIF / CUT);
    float s    = __sinf(ang);
    float c    = __cosf(ang);
    float fc2  = 0.25f * (1.0f + c);                   // 0.5 * fcut
    float dfc2 = -0.25f * (PIF / CUT) * s;
    float dens = 0.f, ddens = 0.f, pair = 0.f, dpair = 0.f;
#pragma unroll 8
    for (int k = 0; k < NB; ++k) {
        float d   = u - k * STEP;
        float ek  = __expf(-GAM * d * d);
        float dek = -2.0f * GAM * d * ek;
        float bk  = ek * fc2;
        float dbk = fmaf(dek, fc2, ek * dfc2);
        dens  = fmaf(bk,  spd[k], dens);
        ddens = fmaf(dbk, spd[k], ddens);
        pair  = fmaf(bk,  pp[k],  pair);
        dpair = fmaf(dbk, pp[k],  dpair);
    }
    return make_float4(dens, ddens, pair, dpair);
}

// Block-wide sum of v, then one atomicAdd to *target. All threads must call.
__device__ __forceinline__ void block_reduce_add(float v, float* target) {
#pragma unroll
    for (int o = 32; o > 0; o >>= 1) v += __shfl_down(v, o, 64);
    __shared__ float wsum[8];
    int lane = threadIdx.x & 63;
    int wid  = threadIdx.x >> 6;
    if (lane == 0) wsum[wid] = v;
    __syncthreads();
    if (threadIdx.x == 0) {
        float s = 0.f;
        int nw = (blockDim.x + 63) >> 6;
        for (int i = 0; i < nw; ++i) s += wsum[i];
        atomicAdd(target, s);
    }
}

template <bool STORE>
__global__ void edge_pass1(const float* __restrict__ r,
                           const int*   __restrict__ dst,
                           const float* __restrict__ phi_d,
                           const float* __restrict__ phi_p,
                           float* __restrict__ local,
                           float* __restrict__ A,
                           float* __restrict__ B,
                           float* __restrict__ energy,
                           int E) {
    __shared__ float spd[NB], pp[NB];
    int t = threadIdx.x;
    if (t < NB) {
        spd[t] = log1pf(__expf(phi_d[t]));   // softplus
        pp[t]  = phi_p[t];
    }
    __syncthreads();
    int e = blockIdx.x * blockDim.x + t;
    float epair = 0.f;
    if (e < E) {
        float x = r[3*e+0], y = r[3*e+1], z = r[3*e+2];
        float u = sqrtf(fmaf(x, x, fmaf(y, y, z*z)));
        float4 q = spline_eval(u, spd, pp);
        float inv = 1.0f / u;
        atomicAdd(&local[dst[e]], q.x);
        if (STORE) {
            A[e] = q.y * inv;                               // ddens / u
            B[e] = (q.w - q.z * inv) * inv * inv;           // (dpair - pair/u)/u^2
        }
        epair = q.z * inv;                                  // pair / u
    }
    block_reduce_add(epair, energy);
}

__global__ void node_pass(const float* __restrict__ local,
                          const float* __restrict__ w,     // emb_weights [5]
                          float* __restrict__ Fp,
                          float* __restrict__ energy,
                          int N) {
    int n = blockIdx.x * blockDim.x + threadIdx.x;
    float Fv = 0.f;
    if (n < N) {
        float x  = local[n];
        float w0 = w[0], w1 = w[1], w2 = w[2], w3 = w[3], w4 = w[4];
        float sq = sqrtf(x);
        float x2 = x * x;
        Fv = 2.f*w0*sq + w1*x + 0.5f*w2*x2 + (1.f/6.f)*w3*x2*x + (1.f/24.f)*w4*x2*x2;
        // F'(x); inf at x==0 matches JAX grad of x**0.5 — such nodes have no
        // in-edges so Fp is never gathered.
        Fp[n] = w0 / sq + w1 + w2*x + 0.5f*w3*x2 + (1.f/6.f)*w4*x2*x;
    }
    block_reduce_add(Fv, energy);
}

template <bool STORE>
__global__ void edge_pass2(const float* __restrict__ r,
                           const int*   __restrict__ src,
                           const int*   __restrict__ dst,
                           const float* __restrict__ A,
                           const float* __restrict__ B,
                           const float* __restrict__ Fp,
                           const float* __restrict__ phi_d,
                           const float* __restrict__ phi_p,
                           float* __restrict__ forces,
                           int E) {
    __shared__ float spd[NB], pp[NB];
    if (!STORE) {
        int t = threadIdx.x;
        if (t < NB) {
            spd[t] = log1pf(__expf(phi_d[t]));
            pp[t]  = phi_p[t];
        }
        __syncthreads();
    }
    int e = blockIdx.x * blockDim.x + threadIdx.x;
    if (e >= E) return;
    float x = r[3*e+0], y = r[3*e+1], z = r[3*e+2];
    int sn = src[e], dn = dst[e];
    float g;
    if (STORE) {
        g = fmaf(Fp[dn], A[e], B[e]);
    } else {
        float u = sqrtf(fmaf(x, x, fmaf(y, y, z*z)));
        float4 q = spline_eval(u, spd, pp);
        float inv = 1.0f / u;
        g = Fp[dn] * (q.y * inv) + (q.w - q.z * inv) * inv * inv;
    }
    float fx = g * x, fy = g * y, fz = g * z;
    atomicAdd(&forces[3*sn+0],  fx);
    atomicAdd(&forces[3*sn+1],  fy);
    atomicAdd(&forces[3*sn+2],  fz);
    atomicAdd(&forces[3*dn+0], -fx);
    atomicAdd(&forces[3*dn+1], -fy);
    atomicAdd(&forces[3*dn+2], -fz);
}

extern "C" void kernel_launch(void* const* d_in, const int* in_sizes, int n_in,
                              void* d_out, int out_size, void* d_ws, size_t ws_size,
                              hipStream_t stream) {
    const float* r     = (const float*)d_in[0];
    const int*   src   = (const int*)  d_in[1];
    const int*   dst   = (const int*)  d_in[2];
    const float* phi_d = (const float*)d_in[3];
    const float* phi_p = (const float*)d_in[4];
    const float* w     = (const float*)d_in[5];
    float* out = (float*)d_out;          // out[0] = energy, out[1..] = forces [N,3]

    int E = in_sizes[1];                 // src count
    int N = (out_size - 1) / 3;

    // ws layout: local[N] | Fp[N] | A[E] | B[E]
    float* local = (float*)d_ws;
    float* Fp    = local + N;
    float* A     = Fp + N;
    float* B     = A + E;
    size_t need  = (size_t)(2 * N + 2 * E) * sizeof(float);
    bool store = ws_size >= need;

    hipMemsetAsync(d_out, 0, (size_t)out_size * sizeof(float), stream);
    hipMemsetAsync(local, 0, (size_t)N * sizeof(float), stream);

    int be = (E + 255) / 256;
    int bn = (N + 255) / 256;

    if (store) {
        edge_pass1<true ><<<be, 256, 0, stream>>>(r, dst, phi_d, phi_p, local, A, B, out, E);
    } else {
        edge_pass1<false><<<be, 256, 0, stream>>>(r, dst, phi_d, phi_p, local, nullptr, nullptr, out, E);
    }
    node_pass<<<bn, 256, 0, stream>>>(local, w, Fp, out, N);
    if (store) {
        edge_pass2<true ><<<be, 256, 0, stream>>>(r, src, dst, A, B, Fp, phi_d, phi_p, out + 1, E);
    } else {
        edge_pass2<false><<<be, 256, 0, stream>>>(r, src, dst, nullptr, nullptr, Fp, phi_d, phi_p, out + 1, E);
    }
}

// Round 4
// 321.200 us; speedup vs baseline: 1.0230x; 1.0230x over previous
//
#include <hip/hip_runtime.h>
#include <cmath>

#define NB 128
#define WIN 48                                   // truncated Gaussian window
static constexpr float CUT  = 6.0f;
static constexpr float STEP = CUT / (NB - 1);
static constexpr float GAM  = (NB - 1) / CUT;    // 1 / mean spacing
static constexpr float PIF  = 3.14159265358979f;

// Hardware fp32 atomic (global_atomic_add_f32). d_out/d_ws are coarse-grained
// device allocations, so unsafeAtomicAdd is exact-semantics here; the default
// atomicAdd compiles to a CAS loop (R1 counters: 150 MB WRITE_SIZE, 244 us).
__device__ __forceinline__ void atomic_add_f32(float* p, float v) {
    unsafeAtomicAdd(p, v);
}

// Evaluate density/pair splines and radial derivatives at bond length u.
// co[k] = {softplus(phi_density[k]), phi_pair[k]} staged in LDS.
// Only centers within ~1.1 of u contribute: exp(-21.17*1.1^2) ~ 7e-12.
__device__ __forceinline__ float4 spline_eval(float u, const float2* __restrict__ co) {
    float ang  = u * (PIF / CUT);
    float s    = __sinf(ang);
    float c    = __cosf(ang);
    float fc2  = 0.25f * (1.0f + c);                   // 0.5 * fcut
    float dfc2 = -0.25f * (PIF / CUT) * s;
    int k0 = (int)ceilf((u - 1.1f) * (1.0f / STEP));
    k0 = max(0, min(NB - WIN, k0));
    float d = u - k0 * STEP;                           // decreases by STEP each iter
    float dens = 0.f, ddens = 0.f, pair = 0.f, dpair = 0.f;
#pragma unroll 8
    for (int j = 0; j < WIN; ++j) {
        float2 w  = co[k0 + j];
        float ek  = __expf(-GAM * d * d);
        float dek = -2.0f * GAM * d * ek;
        float bk  = ek * fc2;
        float dbk = fmaf(dek, fc2, ek * dfc2);
        dens  = fmaf(bk,  w.x, dens);
        ddens = fmaf(dbk, w.x, ddens);
        pair  = fmaf(bk,  w.y, pair);
        dpair = fmaf(dbk, w.y, dpair);
        d -= STEP;
    }
    return make_float4(dens, ddens, pair, dpair);
}

__device__ __forceinline__ void load_coeffs(const float* __restrict__ phi_d,
                                            const float* __restrict__ phi_p,
                                            float2* co) {
    int t = threadIdx.x;
    if (t < NB) {
        float2 w;
        w.x = log1pf(__expf(phi_d[t]));   // softplus
        w.y = phi_p[t];
        co[t] = w;
    }
    __syncthreads();
}

// Block-wide sum of v, then one atomicAdd to *target. All threads must call.
__device__ __forceinline__ void block_reduce_add(float v, float* target) {
#pragma unroll
    for (int o = 32; o > 0; o >>= 1) v += __shfl_down(v, o, 64);
    __shared__ float wsum[8];
    int lane = threadIdx.x & 63;
    int wid  = threadIdx.x >> 6;
    if (lane == 0) wsum[wid] = v;
    __syncthreads();
    if (threadIdx.x == 0) {
        float s = 0.f;
        int nw = (blockDim.x + 63) >> 6;
        for (int i = 0; i < nw; ++i) s += wsum[i];
        atomic_add_f32(target, s);
    }
}

__global__ void edge_pass1(const float* __restrict__ r,
                           const int*   __restrict__ dst,
                           const float* __restrict__ phi_d,
                           const float* __restrict__ phi_p,
                           float* __restrict__ local,
                           float* __restrict__ A,
                           float* __restrict__ B,
                           float* __restrict__ energy,
                           int E) {
    __shared__ float2 co[NB];
    load_coeffs(phi_d, phi_p, co);
    int e = blockIdx.x * blockDim.x + threadIdx.x;
    float epair = 0.f;
    if (e < E) {
        float x = r[3*e+0], y = r[3*e+1], z = r[3*e+2];
        float u = sqrtf(fmaf(x, x, fmaf(y, y, z*z)));
        float4 q = spline_eval(u, co);
        float inv = 1.0f / u;
        atomic_add_f32(&local[dst[e]], q.x);
        A[e] = q.y * inv;                               // ddens / u
        B[e] = (q.w - q.z * inv) * inv * inv;           // (dpair - pair/u)/u^2
        epair = q.z * inv;                              // pair / u
    }
    block_reduce_add(epair, energy);
}

__global__ void node_pass(const float* __restrict__ local,
                          const float* __restrict__ w,     // emb_weights [5]
                          float* __restrict__ Fp,
                          float* __restrict__ energy,
                          int N) {
    int n = blockIdx.x * blockDim.x + threadIdx.x;
    float Fv = 0.f;
    if (n < N) {
        float x  = local[n];
        float w0 = w[0], w1 = w[1], w2 = w[2], w3 = w[3], w4 = w[4];
        float sq = sqrtf(x);
        float x2 = x * x;
        Fv = 2.f*w0*sq + w1*x + 0.5f*w2*x2 + (1.f/6.f)*w3*x2*x + (1.f/24.f)*w4*x2*x2;
        // F'(x); inf at x==0 matches JAX grad of x**0.5 — such nodes have no
        // in-edges so Fp is never gathered.
        Fp[n] = w0 / sq + w1 + w2*x + 0.5f*w3*x2 + (1.f/6.f)*w4*x2*x;
    }
    block_reduce_add(Fv, energy);
}

__global__ void edge_pass2(const float* __restrict__ r,
                           const int*   __restrict__ src,
                           const int*   __restrict__ dst,
                           const float* __restrict__ A,
                           const float* __restrict__ B,
                           const float* __restrict__ Fp,
                           float* __restrict__ forces,
                           int E) {
    int e = blockIdx.x * blockDim.x + threadIdx.x;
    if (e >= E) return;
    float x = r[3*e+0], y = r[3*e+1], z = r[3*e+2];
    int sn = src[e], dn = dst[e];
    float g = fmaf(Fp[dn], A[e], B[e]);
    float fx = g * x, fy = g * y, fz = g * z;
    atomic_add_f32(&forces[3*sn+0],  fx);
    atomic_add_f32(&forces[3*sn+1],  fy);
    atomic_add_f32(&forces[3*sn+2],  fz);
    atomic_add_f32(&forces[3*dn+0], -fx);
    atomic_add_f32(&forces[3*dn+1], -fy);
    atomic_add_f32(&forces[3*dn+2], -fz);
}

extern "C" void kernel_launch(void* const* d_in, const int* in_sizes, int n_in,
                              void* d_out, int out_size, void* d_ws, size_t ws_size,
                              hipStream_t stream) {
    const float* r     = (const float*)d_in[0];
    const int*   src   = (const int*)  d_in[1];
    const int*   dst   = (const int*)  d_in[2];
    const float* phi_d = (const float*)d_in[3];
    const float* phi_p = (const float*)d_in[4];
    const float* w     = (const float*)d_in[5];
    float* out = (float*)d_out;          // out[0] = energy, out[1..] = forces [N,3]

    int E = in_sizes[1];                 // src count
    int N = (out_size - 1) / 3;

    // ws layout: local[N] | Fp[N] | A[E] | B[E]
    float* local = (float*)d_ws;
    float* Fp    = local + N;
    float* A     = Fp + N;
    float* B     = A + E;

    hipMemsetAsync(d_out, 0, (size_t)out_size * sizeof(float), stream);
    hipMemsetAsync(local, 0, (size_t)N * sizeof(float), stream);

    int be = (E + 255) / 256;
    int bn = (N + 255) / 256;

    edge_pass1<<<be, 256, 0, stream>>>(r, dst, phi_d, phi_p, local, A, B, out, E);
    node_pass <<<bn, 256, 0, stream>>>(local, w, Fp, out, N);
    edge_pass2<<<be, 256, 0, stream>>>(r, src, dst, A, B, Fp, out + 1, E);
}